// Round 5
// baseline (384.329 us; speedup 1.0000x reference)
//
#include <hip/hip_runtime.h>
#include <hip/hip_bf16.h>

#define KK 9
#define PADK 4
#define CIN 64
#define COUT 64
#define LSEQ 131072
#define NB 4
#define TILEL 128         // l-extent of a block tile
#define XROWS 136         // TILEL + KK - 1
#define XRS 72            // xt row stride (bf16); 144 B rows -> uniform 8/bank reads
#define NTILES 1024       // LSEQ / TILEL (per batch)
#define NPART 64
#define TPB 4             // tiles per block (pipelined)
#define NBLK 1024         // grid size; NBLK*TPB = NB*NTILES

typedef __attribute__((ext_vector_type(8))) short v8s;
typedef __attribute__((ext_vector_type(4))) float v4f;

__device__ __forceinline__ unsigned short f2bf(float f) {
  __hip_bfloat16 h = __float2bfloat16(f);
  return *reinterpret_cast<unsigned short*>(&h);
}
__device__ __forceinline__ float bf2f(unsigned short s) {
  return __uint_as_float(((unsigned)s) << 16);
}

__device__ __forceinline__ void store_o(float* p, float v) { *p = v; }
__device__ __forceinline__ void store_o(__hip_bfloat16* p, float v) { *p = __float2bfloat16(v); }

// ---------------------------------------------------------------------------
// Repack W[Cout][Cin][K] fp32 -> bf16 A-fragments for mfma_f32_16x16x32_bf16.
// A-layout: lane holds A[m = lane&15][kdim = (lane>>4)*8 + j], j=0..7.
// ---------------------------------------------------------------------------
__global__ void wtrans_kernel(const float* __restrict__ W, v8s* __restrict__ Wt) {
  int t = blockIdx.x * 256 + threadIdx.x;
  if (t >= KK * 2 * 4 * 64) return;
  int lane = t & 63;
  int frag = t >> 6;
  int mblk = frag & 3;
  int s    = (frag >> 2) & 1;
  int k    = frag >> 3;
  int m = lane & 15, q = lane >> 4;
  int o = mblk * 16 + m;
  union { v8s v; unsigned short h[8]; } u;
#pragma unroll
  for (int j = 0; j < 8; ++j) {
    int c = 32 * s + q * 8 + j;
    u.h[j] = f2bf(W[(o * CIN + c) * KK + k]);
  }
  Wt[t] = u.v;
}

// ---------------------------------------------------------------------------
// Pipelined weighted conv. Each block runs TPB tiles of 64(o) x 128(l):
//   iter i: [convert regs -> LDS buf p, halo, (i==0: gaussian)] barrier
//           [issue global loads for tile i+1 (stay in flight through compute);
//            waves 2-3 also compute gaussian(i+1) -> wt[p^1]]
//           [k-loop on buf p] [epilogue stores tile i]
// One barrier per tile; loads issued AFTER it so the barrier's vmcnt(0) drain
// does not flush them. Telescoped accumulation as in R2-R4.
// ---------------------------------------------------------------------------
template <typename OutT>
__global__ __launch_bounds__(256, 3)
void conv_kernel(const float* __restrict__ x, const float* __restrict__ coords,
                 const v8s* __restrict__ Wt, OutT* __restrict__ cv,
                 float* __restrict__ stat_sum, float* __restrict__ stat_sq) {
  __shared__ __align__(16) __hip_bfloat16 xt[2][XROWS][XRS];
  __shared__ float wt[2][KK][TILEL];

  const int tid  = threadIdx.x;
  const int wv   = tid >> 6;
  const int wo   = wv & 1;                    // o-half (32 rows)
  const int wl   = wv >> 1;                   // l-half (64 cols)
  const int lane = tid & 63;
  const int m = lane & 15;
  const int q = lane >> 4;
  const int cg = tid & 7;                     // staging: channel group (8 ch)
  const int lc = tid >> 3;                    // staging: l-chunk 0..31 (4 l)
  const int c8 = cg * 8;

  float4 f[8];                                // pipelined x-stage registers
  float  hl[4];                               // pipelined halo registers (tid<128)

  // ---- prologue: issue loads for tile 0 ----
  {
    const int gt = blockIdx.x;
    const int b = gt >> 10, tile = gt & (NTILES - 1);
    const int l0 = tile * TILEL;
    const float* xb = x + (b * CIN) * LSEQ;
#pragma unroll
    for (int t = 0; t < 8; ++t)
      f[t] = *(const float4*)(xb + (c8 + t) * LSEQ + l0 + 4 * lc);
    if (tid < 128) {
      int side = tid >> 6, c = tid & 63;
      hl[0] = hl[1] = hl[2] = hl[3] = 0.f;
      if (side == 0) {
        if (tile != 0)
#pragma unroll
          for (int j = 0; j < 4; ++j) hl[j] = xb[c * LSEQ + l0 - 4 + j];
      } else {
        if (tile != NTILES - 1)
#pragma unroll
          for (int j = 0; j < 4; ++j) hl[j] = xb[c * LSEQ + l0 + TILEL + j];
      }
    }
  }

#pragma unroll 1
  for (int i = 0; i < TPB; ++i) {
    const int p  = i & 1;
    const int gt = blockIdx.x + NBLK * i;
    const int b = gt >> 10, tile = gt & (NTILES - 1);
    const int l0 = tile * TILEL;

    // ---- write phase: regs -> LDS buf p ----
    {
      const float* fp = (const float*)&f[0];
#pragma unroll
      for (int j = 0; j < 4; ++j) {
        union { v8s v; unsigned short h[8]; } u;
#pragma unroll
        for (int t = 0; t < 8; ++t) u.h[t] = f2bf(fp[4 * t + j]);
        *(v8s*)&xt[p][4 + 4 * lc + j][c8] = u.v;
      }
    }
    if (tid < 128) {
      int side = tid >> 6, c = tid & 63;
      if (side == 0) {
#pragma unroll
        for (int j = 0; j < 4; ++j) xt[p][j][c] = __float2bfloat16(hl[j]);
      } else {
#pragma unroll
        for (int j = 0; j < 4; ++j) xt[p][132 + j][c] = __float2bfloat16(hl[j]);
      }
    } else if (i == 0) {
      // gaussian for tile 0 (synchronous, once per block)
      const float* cb = coords + (b * 3) * LSEQ;
      int n = tid - 128;
      float sx = cb[l0 + n], sy = cb[LSEQ + l0 + n], sz = cb[2 * LSEQ + l0 + n];
      float w9[KK];
#pragma unroll
      for (int k = 0; k < KK; ++k) {
        int l = l0 + n + k - PADK;
        float cx = 0.f, cy = 0.f, cz = 0.f;
        if ((unsigned)l < (unsigned)LSEQ) {
          cx = cb[l]; cy = cb[LSEQ + l]; cz = cb[2 * LSEQ + l];
        }
        float dx = cx - sx, dy = cy - sy, dz = cz - sz;
        w9[k] = __expf(-0.5f * (dx * dx + dy * dy + dz * dz));
      }
#pragma unroll
      for (int k = 0; k < KK; ++k)
        wt[p][k][n] = w9[k] - ((k < KK - 1) ? w9[k + 1] : 0.f);
    }
    __syncthreads();

    // ---- issue next tile's loads (in flight through the k-loop) ----
    if (i + 1 < TPB) {
      const int gt2 = blockIdx.x + NBLK * (i + 1);
      const int b2 = gt2 >> 10, tile2 = gt2 & (NTILES - 1);
      const int l02 = tile2 * TILEL;
      const float* xb2 = x + (b2 * CIN) * LSEQ;
#pragma unroll
      for (int t = 0; t < 8; ++t)
        f[t] = *(const float4*)(xb2 + (c8 + t) * LSEQ + l02 + 4 * lc);
      if (tid < 128) {
        int side = tid >> 6, c = tid & 63;
        hl[0] = hl[1] = hl[2] = hl[3] = 0.f;
        if (side == 0) {
          if (tile2 != 0)
#pragma unroll
            for (int j = 0; j < 4; ++j) hl[j] = xb2[c * LSEQ + l02 - 4 + j];
        } else {
          if (tile2 != NTILES - 1)
#pragma unroll
            for (int j = 0; j < 4; ++j) hl[j] = xb2[c * LSEQ + l02 + TILEL + j];
        }
      } else {
        // waves 2-3: gaussian for tile i+1 into the alternate buffer.
        // wt[p^1] was last read before the barrier of iter i -> safe.
        const float* cb2 = coords + (b2 * 3) * LSEQ;
        int n = tid - 128;
        float sx = cb2[l02 + n], sy = cb2[LSEQ + l02 + n], sz = cb2[2 * LSEQ + l02 + n];
        float w9[KK];
#pragma unroll
        for (int k = 0; k < KK; ++k) {
          int l = l02 + n + k - PADK;
          float cx = 0.f, cy = 0.f, cz = 0.f;
          if ((unsigned)l < (unsigned)LSEQ) {
            cx = cb2[l]; cy = cb2[LSEQ + l]; cz = cb2[2 * LSEQ + l];
          }
          float dx = cx - sx, dy = cy - sy, dz = cz - sz;
          w9[k] = __expf(-0.5f * (dx * dx + dy * dy + dz * dz));
        }
#pragma unroll
        for (int k = 0; k < KK; ++k)
          wt[p ^ 1][k][n] = w9[k] - ((k < KK - 1) ? w9[k + 1] : 0.f);
      }
    }

    // ---- MFMA k-loop on buf p ----
    v4f y[2][4], tot[2][4];
#pragma unroll
    for (int a = 0; a < 2; ++a)
#pragma unroll
      for (int j = 0; j < 4; ++j) {
        y[a][j]   = (v4f){0.f, 0.f, 0.f, 0.f};
        tot[a][j] = (v4f){0.f, 0.f, 0.f, 0.f};
      }

    const v8s* wp = Wt + (wo * 2) * 64 + lane;
#pragma unroll 1
    for (int k = 0; k < KK; ++k) {
#pragma unroll
      for (int s = 0; s < 2; ++s) {
        v8s a0 = wp[k * 512 + s * 256];
        v8s a1 = wp[k * 512 + s * 256 + 64];
#pragma unroll
        for (int nbq = 0; nbq < 4; ++nbq) {
          v8s bf = *(const v8s*)&xt[p][wl * 64 + nbq * 16 + m + k][q * 8 + 32 * s];
          y[0][nbq] = __builtin_amdgcn_mfma_f32_16x16x32_bf16(a0, bf, y[0][nbq], 0, 0, 0);
          y[1][nbq] = __builtin_amdgcn_mfma_f32_16x16x32_bf16(a1, bf, y[1][nbq], 0, 0, 0);
        }
      }
#pragma unroll
      for (int nbq = 0; nbq < 4; ++nbq) {
        float d = wt[p][k][wl * 64 + nbq * 16 + m];
#pragma unroll
        for (int mb = 0; mb < 2; ++mb)
#pragma unroll
          for (int r = 0; r < 4; ++r)
            tot[mb][nbq][r] = __builtin_fmaf(d, y[mb][nbq][r], tot[mb][nbq][r]);
      }
    }

    // ---- epilogue for tile i ----
    const int part = gt & (NPART - 1);
    OutT* outb = cv + (b * COUT) * LSEQ;
#pragma unroll
    for (int mb = 0; mb < 2; ++mb) {
#pragma unroll
      for (int r = 0; r < 4; ++r) {
        int o = wo * 32 + mb * 16 + q * 4 + r;
        float s1 = 0.f, s2 = 0.f;
#pragma unroll
        for (int nbq = 0; nbq < 4; ++nbq) {
          float v = tot[mb][nbq][r];
          s1 += v;
          s2 += v * v;
          store_o(&outb[o * LSEQ + l0 + wl * 64 + nbq * 16 + m], v);
        }
#pragma unroll
        for (int off = 1; off < 16; off <<= 1) {
          s1 += __shfl_xor(s1, off, 64);
          s2 += __shfl_xor(s2, off, 64);
        }
        if (m == 0) {
          atomicAdd(&stat_sum[part * COUT + o], s1);
          atomicAdd(&stat_sq [part * COUT + o], s2);
        }
      }
    }
  }
}

// ---------------------------------------------------------------------------
// BN finalize: scale = gamma*rsqrt(var+eps), shift = beta - mean*scale.
// ---------------------------------------------------------------------------
__global__ void finalize_kernel(const float* __restrict__ stat_sum,
                                const float* __restrict__ stat_sq,
                                const float* __restrict__ gamma,
                                const float* __restrict__ beta,
                                float* __restrict__ ss) {
  int o = threadIdx.x;
  float s1 = 0.f, s2 = 0.f;
  for (int p = 0; p < NPART; ++p) {
    s1 += stat_sum[p * COUT + o];
    s2 += stat_sq [p * COUT + o];
  }
  const float invN = 1.0f / (float)(NB * LSEQ);
  float mean = s1 * invN;
  float var  = s2 * invN - mean * mean;   // biased, matches jnp.var
  float sc = gamma[o] * rsqrtf(var + 1e-5f);
  ss[o]        = sc;
  ss[COUT + o] = beta[o] - mean * sc;
}

// ---- BN apply + ReLU; one block = 2048 contiguous elems in one channel ----
__global__ __launch_bounds__(256)
void scale_f32_kernel(float* __restrict__ data, const float* __restrict__ ss) {
  const int blk = blockIdx.x;
  const int ch = (blk >> 6) & 63;
  const float sc = ss[ch];
  const float sh = ss[COUT + ch];
  const int base = blk * 2048 + threadIdx.x * 8;
  float4 a = *(float4*)(data + base);
  float4 b = *(float4*)(data + base + 4);
  a.x = fmaxf(fmaf(a.x, sc, sh), 0.f);
  a.y = fmaxf(fmaf(a.y, sc, sh), 0.f);
  a.z = fmaxf(fmaf(a.z, sc, sh), 0.f);
  a.w = fmaxf(fmaf(a.w, sc, sh), 0.f);
  b.x = fmaxf(fmaf(b.x, sc, sh), 0.f);
  b.y = fmaxf(fmaf(b.y, sc, sh), 0.f);
  b.z = fmaxf(fmaf(b.z, sc, sh), 0.f);
  b.w = fmaxf(fmaf(b.w, sc, sh), 0.f);
  *(float4*)(data + base)     = a;
  *(float4*)(data + base + 4) = b;
}

__global__ __launch_bounds__(256)
void scale_bf16_kernel(const __hip_bfloat16* __restrict__ cvin,
                       const float* __restrict__ ss, float* __restrict__ out) {
  const int blk = blockIdx.x;
  const int ch = (blk >> 6) & 63;
  const float sc = ss[ch];
  const float sh = ss[COUT + ch];
  const int base = blk * 2048 + threadIdx.x * 8;
  union { v8s v; unsigned short h[8]; } u;
  u.v = *(const v8s*)(cvin + base);
  float r[8];
#pragma unroll
  for (int i = 0; i < 8; ++i)
    r[i] = fmaxf(fmaf(bf2f(u.h[i]), sc, sh), 0.f);
  *(float4*)(out + base)     = make_float4(r[0], r[1], r[2], r[3]);
  *(float4*)(out + base + 4) = make_float4(r[4], r[5], r[6], r[7]);
}

extern "C" void kernel_launch(void* const* d_in, const int* in_sizes, int n_in,
                              void* d_out, int out_size, void* d_ws, size_t ws_size,
                              hipStream_t stream) {
  const float* x      = (const float*)d_in[0];
  const float* coords = (const float*)d_in[1];
  const float* W      = (const float*)d_in[2];
  // d_in[3] = bias: cancels under training-mode BatchNorm; unused.
  const float* gamma  = (const float*)d_in[4];
  const float* beta   = (const float*)d_in[5];
  float* out = (float*)d_out;
  char* ws = (char*)d_ws;

  float* stat_sum = (float*)(ws);            // 64*64 f32
  float* stat_sq  = (float*)(ws + 16384);    // 64*64 f32
  float* ss       = (float*)(ws + 32768);    // 128 f32
  v8s*   Wt       = (v8s*)(ws + 40960);      // 73728 B
  __hip_bfloat16* scratch = (__hip_bfloat16*)(ws + 131072); // 64 MiB (optional)

  const size_t need_bf16 = (size_t)131072 + (size_t)NB * COUT * LSEQ * 2;
  const bool bf16_path = ws_size >= need_bf16;

  hipMemsetAsync(ws, 0, 32768, stream);
  wtrans_kernel<<<18, 256, 0, stream>>>(W, Wt);

  if (bf16_path) {
    conv_kernel<__hip_bfloat16><<<NBLK, 256, 0, stream>>>(
        x, coords, Wt, scratch, stat_sum, stat_sq);
    finalize_kernel<<<1, COUT, 0, stream>>>(stat_sum, stat_sq, gamma, beta, ss);
    scale_bf16_kernel<<<(NB * COUT * (LSEQ / 2048)), 256, 0, stream>>>(scratch, ss, out);
  } else {
    conv_kernel<float><<<NBLK, 256, 0, stream>>>(
        x, coords, Wt, out, stat_sum, stat_sq);
    finalize_kernel<<<1, COUT, 0, stream>>>(stat_sum, stat_sq, gamma, beta, ss);
    scale_f32_kernel<<<(NB * COUT * (LSEQ / 2048)), 256, 0, stream>>>(out, ss);
  }
}